// Round 14
// baseline (26.439 us; speedup 1.0000x reference)
//
#include <hip/hip_runtime.h>
#include <hip/hip_bf16.h>
#include <math.h>

#define IN_DIM 512
#define NC 100
#define NN 63
#define NE 16
#define BATCH 8192
#define XP 516   // padded x row stride in floats (516 mod 32 = 4 -> 2-way-free gathers)
#define RW 68    // red row stride (68 mod 32 = 4)

typedef __attribute__((ext_vector_type(8))) short bf16x8;
typedef __attribute__((ext_vector_type(4))) float f32x4;

static __device__ __forceinline__ ushort bf16_bits(__hip_bfloat16 h) {
  union { __hip_bfloat16 b; ushort u; } cv; cv.b = h; return cv.u;
}

// ---------------- Kernel 1: fused prep = B-fragments + per-node argmax (verbatim r8)
__global__ __launch_bounds__(256) void prep_kernel(
    const float* __restrict__ T, const float* __restrict__ L,
    ushort* __restrict__ Bfrag, float* __restrict__ tmax, int* __restrict__ dstar) {
  const int tid = threadIdx.x;
  const int bid = blockIdx.x;

  // --- L -> B-fragments [kc][hl][cf][lane][8] bf16 hi/lo ---
  {
    const int i = bid * 256 + tid;  // 0..262143
    const int j = i & 7;
    const int lane = (i >> 3) & 63;
    const int cf = (i >> 9) & 7;
    const int hl = (i >> 12) & 1;
    const int kc = i >> 13;
    const int k = kc * 32 + (lane >> 4) * 8 + j;
    const int c = cf * 16 + (lane & 15);
    const float val = (c < NC) ? L[(size_t)k * NC + c] : 0.0f;
    const __hip_bfloat16 hb = __float2bfloat16(val);
    ushort outv;
    if (hl == 0) {
      outv = bf16_bits(hb);
    } else {
      const __hip_bfloat16 lb = __float2bfloat16(val - __bfloat162float(hb));
      outv = bf16_bits(lb);
    }
    Bfrag[i] = outv;
  }

  // --- per-node argmax/max over IN_DIM: wave 0 of blocks 0..1007 ---
  if (bid < NE * NN && tid < 64) {
    const float4* row = reinterpret_cast<const float4*>(T + (size_t)bid * IN_DIM);
    const int lane = tid;
    float best = -INFINITY;
    int bidx = 0;
#pragma unroll
    for (int i = 0; i < 2; ++i) {
      const int f4 = lane + 64 * i;
      const float4 v = row[f4];
      const int base = f4 * 4;
      if (v.x > best) { best = v.x; bidx = base; }
      if (v.y > best) { best = v.y; bidx = base + 1; }
      if (v.z > best) { best = v.z; bidx = base + 2; }
      if (v.w > best) { best = v.w; bidx = base + 3; }
    }
#pragma unroll
    for (int off = 32; off; off >>= 1) {
      const float ov = __shfl_xor(best, off);
      const int oi = __shfl_xor(bidx, off);
      if (ov > best || (ov == best && oi < bidx)) { best = ov; bidx = oi; }
    }
    if (lane == 0) {
      tmax[bid] = best;
      dstar[bid] = bidx;
    }
  }
}

// ---------------- Kernel F: 32 rows/block, 1024 thr = 16 waves = 4 waves/SIMD -------
// Wave w = estimator w: kc = 2w+t (t=0,1), both 16-row tiles. B in 2-cf chunks.
__global__ __launch_bounds__(1024, 4) void forest_fused_kernel(
    const float* __restrict__ x, const ushort* __restrict__ Bfrag,
    const float* __restrict__ tmaxg, const int* __restrict__ dstarg,
    float* __restrict__ out) {
  __shared__ __align__(16) float xl[32 * XP];         // 66048 B
  __shared__ __align__(16) int2 tds[NE * 64];         // 8192 B (+1 shift)
  __shared__ __align__(16) float red[16 * 16 * RW];   // 69632 B -> total 143872 B
  const int tid = threadIdx.x;
  const int b0 = blockIdx.x * 32;
  const int w = tid >> 6, lane = tid & 63;

  // ---- stage 32 x rows (f32 exact) + packed node table ----
  {
    const float4* xg = reinterpret_cast<const float4*>(x + (size_t)b0 * IN_DIM);
#pragma unroll
    for (int i = 0; i < 4; ++i) {
      const int idx = tid + i * 1024;   // 0..4095
      const int r = idx >> 7, c4 = idx & 127;
      *reinterpret_cast<float4*>(&xl[r * XP + c4 * 4]) = xg[r * 128 + c4];
    }
    for (int i = tid; i < NE * NN; i += 1024) {
      const int e = (i * 1041) >> 16;   // i/63 exact for i<1008
      const int n = i - e * 63;
      tds[e * 64 + 1 + n] = make_int2(dstarg[i], __float_as_int(tmaxg[i]));
    }
  }
  __syncthreads();

  const int r = lane & 15;
  const int lgq = lane >> 4;
  const float* xr0 = &xl[r * XP];
  const float* xr1 = &xl[(r + 16) * XP];
  const bf16x8* bf = reinterpret_cast<const bf16x8*>(Bfrag);

  f32x4 acc0[8], acc1[8];
#pragma unroll
  for (int cf = 0; cf < 8; ++cf) { acc0[cf] = (f32x4)0.0f; acc1[cf] = (f32x4)0.0f; }

  for (int t = 0; t < 2; ++t) {
    const int kc = w * 2 + t;        // wave w = estimator w
    const int e = w;
    const int lg = t * 4 + lgq;
    const size_t bbase = (size_t)kc * 1024;

    // ---- packed table reads (7 LDS instrs; shared across both row-tiles) ----
    const int2* tb = &tds[e * 64];
    const int2 T1 = tb[1];
    const int2 T2 = tb[2 + (lg >> 2)];
    const int2 T3 = tb[4 + (lg >> 1)];
    const int2 T4 = tb[8 + lg];
    const int4 P5 = *reinterpret_cast<const int4*>(&tb[16 + 2 * lg]);
    const int4 Q0 = *reinterpret_cast<const int4*>(&tb[32 + 4 * lg]);
    const int4 Q1 = *reinterpret_cast<const int4*>(&tb[34 + 4 * lg]);

    bf16x8 Ah0, Al0, Ah1, Al1;
    // A-gen (r9 math verbatim, table values from registers)
    auto agen = [&](const float* xr, bf16x8& Ah, bf16x8& Al) {
      const float s1 = floorf(__int_as_float(T1.y) - xr[T1.x]);
      const float s2 = floorf(__int_as_float(T2.y) - xr[T2.x]);
      const float s3 = floorf(__int_as_float(T3.y) - xr[T3.x]);
      const float s4 = floorf(__int_as_float(T4.y) - xr[T4.x]);
      const float s5a = floorf(__int_as_float(P5.y) - xr[P5.x]);
      const float s5b = floorf(__int_as_float(P5.w) - xr[P5.z]);
      const float s60 = floorf(__int_as_float(Q0.y) - xr[Q0.x]);
      const float s61 = floorf(__int_as_float(Q0.w) - xr[Q0.z]);
      const float s62 = floorf(__int_as_float(Q1.y) - xr[Q1.x]);
      const float s63 = floorf(__int_as_float(Q1.w) - xr[Q1.z]);
      const float f1 = ((lg >> 2) & 1) ? 1.0f - s1 : s1;
      const float f2 = ((lg >> 1) & 1) ? 1.0f - s2 : s2;
      const float f3 = (lg & 1) ? 1.0f - s3 : s3;
      const float stem = f1 * f2 * f3;
      const float qa = stem * s4, qb = stem * (1.0f - s4);
      const float w00 = qa * s5a, w01 = qa * (1.0f - s5a);
      const float w10 = qb * s5b, w11 = qb * (1.0f - s5b);
      float p[8];
      p[0] = w00 * s60; p[1] = w00 * (1.0f - s60);
      p[2] = w01 * s61; p[3] = w01 * (1.0f - s61);
      p[4] = w10 * s62; p[5] = w10 * (1.0f - s62);
      p[6] = w11 * s63; p[7] = w11 * (1.0f - s63);
      union { ushort u[8]; bf16x8 v; } H, Lo;
#pragma unroll
      for (int i2 = 0; i2 < 8; ++i2) {
        const __hip_bfloat16 hb = __float2bfloat16(p[i2]);
        const float hf = __bfloat162float(hb);
        H.u[i2] = bf16_bits(hb);
        Lo.u[i2] = bf16_bits(__float2bfloat16(p[i2] - hf));
      }
      Ah = H.v; Al = Lo.v;
    };
    agen(xr0, Ah0, Al0);
    agen(xr1, Ah1, Al1);

    // ---- 4 B-chunks of 2 cf; TLP (4 waves/SIMD) hides chunk load latency ----
#pragma unroll
    for (int bc = 0; bc < 4; ++bc) {
      const int cf0 = bc * 2;
      bf16x8 BH0 = bf[bbase + (size_t)cf0 * 64 + lane];
      bf16x8 BL0 = bf[bbase + 512 + (size_t)cf0 * 64 + lane];
      bf16x8 BH1 = bf[bbase + (size_t)(cf0 + 1) * 64 + lane];
      bf16x8 BL1 = bf[bbase + 512 + (size_t)(cf0 + 1) * 64 + lane];
      acc0[cf0] = __builtin_amdgcn_mfma_f32_16x16x32_bf16(Ah0, BH0, acc0[cf0], 0, 0, 0);
      acc0[cf0] = __builtin_amdgcn_mfma_f32_16x16x32_bf16(Al0, BH0, acc0[cf0], 0, 0, 0);
      acc0[cf0] = __builtin_amdgcn_mfma_f32_16x16x32_bf16(Ah0, BL0, acc0[cf0], 0, 0, 0);
      acc0[cf0] = __builtin_amdgcn_mfma_f32_16x16x32_bf16(Al0, BL0, acc0[cf0], 0, 0, 0);
      acc1[cf0] = __builtin_amdgcn_mfma_f32_16x16x32_bf16(Ah1, BH0, acc1[cf0], 0, 0, 0);
      acc1[cf0] = __builtin_amdgcn_mfma_f32_16x16x32_bf16(Al1, BH0, acc1[cf0], 0, 0, 0);
      acc1[cf0] = __builtin_amdgcn_mfma_f32_16x16x32_bf16(Ah1, BL0, acc1[cf0], 0, 0, 0);
      acc1[cf0] = __builtin_amdgcn_mfma_f32_16x16x32_bf16(Al1, BL0, acc1[cf0], 0, 0, 0);
      acc0[cf0 + 1] = __builtin_amdgcn_mfma_f32_16x16x32_bf16(Ah0, BH1, acc0[cf0 + 1], 0, 0, 0);
      acc0[cf0 + 1] = __builtin_amdgcn_mfma_f32_16x16x32_bf16(Al0, BH1, acc0[cf0 + 1], 0, 0, 0);
      acc0[cf0 + 1] = __builtin_amdgcn_mfma_f32_16x16x32_bf16(Ah0, BL1, acc0[cf0 + 1], 0, 0, 0);
      acc0[cf0 + 1] = __builtin_amdgcn_mfma_f32_16x16x32_bf16(Al0, BL1, acc0[cf0 + 1], 0, 0, 0);
      acc1[cf0 + 1] = __builtin_amdgcn_mfma_f32_16x16x32_bf16(Ah1, BH1, acc1[cf0 + 1], 0, 0, 0);
      acc1[cf0 + 1] = __builtin_amdgcn_mfma_f32_16x16x32_bf16(Al1, BH1, acc1[cf0 + 1], 0, 0, 0);
      acc1[cf0 + 1] = __builtin_amdgcn_mfma_f32_16x16x32_bf16(Ah1, BL1, acc1[cf0 + 1], 0, 0, 0);
      acc1[cf0 + 1] = __builtin_amdgcn_mfma_f32_16x16x32_bf16(Al1, BL1, acc1[cf0 + 1], 0, 0, 0);
    }
  }

  // ---- epilogue: per tile, 2 cf-chunks (64 cols), 16-partial reduce, softmax ------
  const int rlo = (lane >> 4) * 4;
  const int cl = lane & 15;
  // thread (row erow = w, col lane) for reduce/softmax: wave w handles row w of tile
  const int erow = w;
  const int ec = lane;

#pragma unroll
  for (int tile = 0; tile < 2; ++tile) {
    float vlo = 0.0f, vhi = 0.0f;
#pragma unroll
    for (int ch = 0; ch < 2; ++ch) {
#pragma unroll
      for (int cf4 = 0; cf4 < 4; ++cf4) {
        const f32x4 a = tile ? acc1[ch * 4 + cf4] : acc0[ch * 4 + cf4];
#pragma unroll
        for (int jj = 0; jj < 4; ++jj)
          red[(w * 16 + rlo + jj) * RW + cf4 * 16 + cl] = a[jj];
      }
      __syncthreads();
      float s = 0.0f;
#pragma unroll
      for (int p = 0; p < 16; ++p) s += red[(p * 16 + erow) * RW + ec];
      if (ch == 0) vlo = s; else vhi = s;
      __syncthreads();
    }
    // wave-wide softmax for row (b0 + tile*16 + erow): cols ec and 64+ec
    const float v2 = (ec + 64 < NC) ? vhi : -INFINITY;
    float m = fmaxf(vlo, v2);
#pragma unroll
    for (int off = 32; off; off >>= 1) m = fmaxf(m, __shfl_xor(m, off));
    const float e1 = __expf(vlo - m);
    const float e2 = (ec + 64 < NC) ? __expf(vhi - m) : 0.0f;
    float ss = e1 + e2;
#pragma unroll
    for (int off = 32; off; off >>= 1) ss += __shfl_xor(ss, off);
    const float inv = 1.0f / ss;
    float* orow = out + (size_t)(b0 + tile * 16 + erow) * NC;
    orow[ec] = e1 * inv;
    if (ec + 64 < NC) orow[ec + 64] = e2 * inv;
  }
}

extern "C" void kernel_launch(void* const* d_in, const int* in_sizes, int n_in,
                              void* d_out, int out_size, void* d_ws, size_t ws_size,
                              hipStream_t stream) {
  const float* x = (const float*)d_in[0];  // (8192, 512)
  const float* T = (const float*)d_in[1];  // (16, 63, 512)
  const float* L = (const float*)d_in[2];  // (16, 64, 100)
  float* out = (float*)d_out;              // (8192, 100)

  char* ws = (char*)d_ws;
  ushort* Bfrag = (ushort*)ws;              // 262144 bf16 = 524288 B
  float* tmax = (float*)(ws + 524288);      // 1008 f32
  int* dstar = (int*)(ws + 528384);         // 1008 i32

  prep_kernel<<<1024, 256, 0, stream>>>(T, L, Bfrag, tmax, dstar);
  forest_fused_kernel<<<BATCH / 32, 1024, 0, stream>>>(x, Bfrag, tmax, dstar, out);
}

// Round 15
// 23.661 us; speedup vs baseline: 1.1174x; 1.1174x over previous
//
#include <hip/hip_runtime.h>
#include <hip/hip_bf16.h>
#include <math.h>

#define IN_DIM 512
#define NC 100
#define NN 63
#define NE 16
#define BATCH 8192
#define XP 516   // padded x row stride in floats (516 mod 32 = 4 -> 2-way-free gathers)

typedef __attribute__((ext_vector_type(8))) short bf16x8;
typedef __attribute__((ext_vector_type(4))) float f32x4;

static __device__ __forceinline__ ushort bf16_bits(__hip_bfloat16 h) {
  union { __hip_bfloat16 b; ushort u; } cv; cv.b = h; return cv.u;
}

// ---------------- Kernel 1: fused prep = B-fragments + per-node argmax (verbatim r8)
__global__ __launch_bounds__(256) void prep_kernel(
    const float* __restrict__ T, const float* __restrict__ L,
    ushort* __restrict__ Bfrag, float* __restrict__ tmax, int* __restrict__ dstar) {
  const int tid = threadIdx.x;
  const int bid = blockIdx.x;

  // --- L -> B-fragments [kc][hl][cf][lane][8] bf16 hi/lo ---
  {
    const int i = bid * 256 + tid;  // 0..262143
    const int j = i & 7;
    const int lane = (i >> 3) & 63;
    const int cf = (i >> 9) & 7;
    const int hl = (i >> 12) & 1;
    const int kc = i >> 13;
    const int k = kc * 32 + (lane >> 4) * 8 + j;
    const int c = cf * 16 + (lane & 15);
    const float val = (c < NC) ? L[(size_t)k * NC + c] : 0.0f;
    const __hip_bfloat16 hb = __float2bfloat16(val);
    ushort outv;
    if (hl == 0) {
      outv = bf16_bits(hb);
    } else {
      const __hip_bfloat16 lb = __float2bfloat16(val - __bfloat162float(hb));
      outv = bf16_bits(lb);
    }
    Bfrag[i] = outv;
  }

  // --- per-node argmax/max over IN_DIM: wave 0 of blocks 0..1007 ---
  if (bid < NE * NN && tid < 64) {
    const float4* row = reinterpret_cast<const float4*>(T + (size_t)bid * IN_DIM);
    const int lane = tid;
    float best = -INFINITY;
    int bidx = 0;
#pragma unroll
    for (int i = 0; i < 2; ++i) {
      const int f4 = lane + 64 * i;
      const float4 v = row[f4];
      const int base = f4 * 4;
      if (v.x > best) { best = v.x; bidx = base; }
      if (v.y > best) { best = v.y; bidx = base + 1; }
      if (v.z > best) { best = v.z; bidx = base + 2; }
      if (v.w > best) { best = v.w; bidx = base + 3; }
    }
#pragma unroll
    for (int off = 32; off; off >>= 1) {
      const float ov = __shfl_xor(best, off);
      const int oi = __shfl_xor(bidx, off);
      if (ov > best || (ov == best && oi < bidx)) { best = ov; bidx = oi; }
    }
    if (lane == 0) {
      tmax[bid] = best;
      dstar[bid] = bidx;
    }
  }
}

// ---------------- Kernel F: r8 forest + cross-t double-buffered B prefetch ----------
__global__ __launch_bounds__(512, 2) void forest_fused_kernel(
    const float* __restrict__ x, const ushort* __restrict__ Bfrag,
    const float* __restrict__ tmaxg, const int* __restrict__ dstarg,
    float* __restrict__ out) {
  __shared__ __align__(16) float xl[32 * XP];          // 66048 B
  __shared__ float tl[NE * NN];                        // 4032 B
  __shared__ int dl[NE * NN];                          // 4032 B
  __shared__ __align__(16) float red[8 * 16 * 128];    // 65536 B (no xl alias!)
  const int tid = threadIdx.x;
  const int b0 = blockIdx.x * 32;
  const int w = tid >> 6, lane = tid & 63;

  // ---- stage 32 x rows (f32 exact) + node tables (verbatim r8) ----
  {
    const float4* xg = reinterpret_cast<const float4*>(x + (size_t)b0 * IN_DIM);
#pragma unroll
    for (int i = 0; i < 8; ++i) {
      const int idx = tid + i * 512;    // 0..4095
      const int r = idx >> 7, c4 = idx & 127;
      *reinterpret_cast<float4*>(&xl[r * XP + c4 * 4]) = xg[r * 128 + c4];
    }
    for (int i = tid; i < NE * NN; i += 512) { tl[i] = tmaxg[i]; dl[i] = dstarg[i]; }
  }
  __syncthreads();

  const int r = lane & 15;
  const int lgq = lane >> 4;
  const float* xr0 = &xl[r * XP];
  const float* xr1 = &xl[(r + 16) * XP];
  const bf16x8* bf = reinterpret_cast<const bf16x8*>(Bfrag);

  // A-gen: verbatim r8 math
  auto agen = [&](const float* xr, int lg, const float* te, const int* de,
                  bf16x8& Ah, bf16x8& Al) {
    const float s1 = floorf(te[0] - xr[de[0]]);
    const int n2 = 1 + (lg >> 2), n3 = 3 + (lg >> 1), n4 = 7 + lg;
    const float s2 = floorf(te[n2] - xr[de[n2]]);
    const float s3 = floorf(te[n3] - xr[de[n3]]);
    const float s4 = floorf(te[n4] - xr[de[n4]]);
    const int n5 = 15 + 2 * lg, n6 = 31 + 4 * lg;
    const float s5a = floorf(te[n5] - xr[de[n5]]);
    const float s5b = floorf(te[n5 + 1] - xr[de[n5 + 1]]);
    const float s60 = floorf(te[n6] - xr[de[n6]]);
    const float s61 = floorf(te[n6 + 1] - xr[de[n6 + 1]]);
    const float s62 = floorf(te[n6 + 2] - xr[de[n6 + 2]]);
    const float s63 = floorf(te[n6 + 3] - xr[de[n6 + 3]]);
    const float f1 = ((lg >> 2) & 1) ? 1.0f - s1 : s1;
    const float f2 = ((lg >> 1) & 1) ? 1.0f - s2 : s2;
    const float f3 = (lg & 1) ? 1.0f - s3 : s3;
    const float stem = f1 * f2 * f3;
    const float qa = stem * s4, qb = stem * (1.0f - s4);
    const float w00 = qa * s5a, w01 = qa * (1.0f - s5a);
    const float w10 = qb * s5b, w11 = qb * (1.0f - s5b);
    float p[8];
    p[0] = w00 * s60; p[1] = w00 * (1.0f - s60);
    p[2] = w01 * s61; p[3] = w01 * (1.0f - s61);
    p[4] = w10 * s62; p[5] = w10 * (1.0f - s62);
    p[6] = w11 * s63; p[7] = w11 * (1.0f - s63);
    union { ushort u[8]; bf16x8 v; } H, Lo;
#pragma unroll
    for (int i2 = 0; i2 < 8; ++i2) {
      const __hip_bfloat16 hb = __float2bfloat16(p[i2]);
      const float hf = __bfloat162float(hb);
      H.u[i2] = bf16_bits(hb);
      Lo.u[i2] = bf16_bits(__float2bfloat16(p[i2] - hf));
    }
    Ah = H.v; Al = Lo.v;
  };

  auto loadB = [&](int kc, bf16x8 (&BH)[8], bf16x8 (&BL)[8]) {
    const size_t bbase = (size_t)kc * 1024;
#pragma unroll
    for (int cf = 0; cf < 8; ++cf) {
      BH[cf] = bf[bbase + (size_t)cf * 64 + lane];
      BL[cf] = bf[bbase + 512 + (size_t)cf * 64 + lane];
    }
  };

  f32x4 acc0[8], acc1[8];
#pragma unroll
  for (int cf = 0; cf < 8; ++cf) { acc0[cf] = (f32x4)0.0f; acc1[cf] = (f32x4)0.0f; }

  bf16x8 B0h[8], B0l[8], B1h[8], B1l[8];
  loadB(w * 4, B0h, B0l);   // prologue: t=0's B

#pragma unroll
  for (int t = 0; t < 4; ++t) {
    const int kc = w * 4 + t;
    const int e = kc >> 1;
    const int lg = (kc & 1) * 4 + lgq;

    // current / next buffers (compile-time after unroll)
    bf16x8(&BH)[8] = (t & 1) ? B1h : B0h;
    bf16x8(&BL)[8] = (t & 1) ? B1l : B0l;
    bf16x8(&BHn)[8] = (t & 1) ? B0h : B1h;
    bf16x8(&BLn)[8] = (t & 1) ? B0l : B1l;

    // ---- issue NEXT t's 16 B loads first: ~500+ cy of agen+MFMA covers them ----
    if (t < 3) loadB(kc + 1, BHn, BLn);

    const float* te = &tl[e * NN];
    const int* de = &dl[e * NN];
    bf16x8 Ah, Al;

    agen(xr0, lg, te, de, Ah, Al);
#pragma unroll
    for (int cf = 0; cf < 8; ++cf) {
      acc0[cf] = __builtin_amdgcn_mfma_f32_16x16x32_bf16(Ah, BH[cf], acc0[cf], 0, 0, 0);
      acc0[cf] = __builtin_amdgcn_mfma_f32_16x16x32_bf16(Al, BH[cf], acc0[cf], 0, 0, 0);
      acc0[cf] = __builtin_amdgcn_mfma_f32_16x16x32_bf16(Ah, BL[cf], acc0[cf], 0, 0, 0);
      acc0[cf] = __builtin_amdgcn_mfma_f32_16x16x32_bf16(Al, BL[cf], acc0[cf], 0, 0, 0);
    }
    agen(xr1, lg, te, de, Ah, Al);
#pragma unroll
    for (int cf = 0; cf < 8; ++cf) {
      acc1[cf] = __builtin_amdgcn_mfma_f32_16x16x32_bf16(Ah, BH[cf], acc1[cf], 0, 0, 0);
      acc1[cf] = __builtin_amdgcn_mfma_f32_16x16x32_bf16(Al, BH[cf], acc1[cf], 0, 0, 0);
      acc1[cf] = __builtin_amdgcn_mfma_f32_16x16x32_bf16(Ah, BL[cf], acc1[cf], 0, 0, 0);
      acc1[cf] = __builtin_amdgcn_mfma_f32_16x16x32_bf16(Al, BL[cf], acc1[cf], 0, 0, 0);
    }
  }

  // ---- epilogue: two passes (rows 0-15, then 16-31) through red (verbatim r8) ----
  const int rlo = (lane >> 4) * 4;
  const int cl = lane & 15;
  const int rr = tid >> 5;   // 0..15
  const int cg = tid & 31;   // 4 cols each

  auto epi = [&](const f32x4 (&ac)[8], int rowbase) {
#pragma unroll
    for (int cf = 0; cf < 8; ++cf)
#pragma unroll
      for (int jj = 0; jj < 4; ++jj)
        red[(w * 16 + rlo + jj) * 128 + cf * 16 + cl] = ac[cf][jj];
    __syncthreads();
    float v[4];
#pragma unroll
    for (int j = 0; j < 4; ++j) {
      const int c = cg * 4 + j;
      float s = red[(0 * 16 + rr) * 128 + c];
#pragma unroll
      for (int pw = 1; pw < 8; ++pw) s += red[(pw * 16 + rr) * 128 + c];
      v[j] = s;
    }
    float m = -INFINITY;
#pragma unroll
    for (int j = 0; j < 4; ++j)
      if (cg * 4 + j < NC) m = fmaxf(m, v[j]);
#pragma unroll
    for (int off = 1; off < 32; off <<= 1) m = fmaxf(m, __shfl_xor(m, off));
    float ev[4];
    float ss = 0.0f;
#pragma unroll
    for (int j = 0; j < 4; ++j) {
      ev[j] = (cg * 4 + j < NC) ? __expf(v[j] - m) : 0.0f;
      ss += ev[j];
    }
#pragma unroll
    for (int off = 1; off < 32; off <<= 1) ss += __shfl_xor(ss, off);
    const float inv = 1.0f / ss;
    if (cg < 25) {
      float* orow = out + (size_t)(b0 + rowbase + rr) * NC + cg * 4;
      *reinterpret_cast<float4*>(orow) =
          make_float4(ev[0] * inv, ev[1] * inv, ev[2] * inv, ev[3] * inv);
    }
  };

  epi(acc0, 0);
  __syncthreads();   // pass-0 reads done before pass-1 overwrites red
  epi(acc1, 16);
}

extern "C" void kernel_launch(void* const* d_in, const int* in_sizes, int n_in,
                              void* d_out, int out_size, void* d_ws, size_t ws_size,
                              hipStream_t stream) {
  const float* x = (const float*)d_in[0];  // (8192, 512)
  const float* T = (const float*)d_in[1];  // (16, 63, 512)
  const float* L = (const float*)d_in[2];  // (16, 64, 100)
  float* out = (float*)d_out;              // (8192, 100)

  char* ws = (char*)d_ws;
  ushort* Bfrag = (ushort*)ws;              // 262144 bf16 = 524288 B
  float* tmax = (float*)(ws + 524288);      // 1008 f32
  int* dstar = (int*)(ws + 528384);         // 1008 i32

  prep_kernel<<<1024, 256, 0, stream>>>(T, L, Bfrag, tmax, dstar);
  forest_fused_kernel<<<BATCH / 32, 512, 0, stream>>>(x, Bfrag, tmax, dstar, out);
}

// Round 16
// 22.059 us; speedup vs baseline: 1.1986x; 1.0726x over previous
//
#include <hip/hip_runtime.h>
#include <hip/hip_bf16.h>
#include <math.h>

#define IN_DIM 512
#define NC 100
#define NN 63
#define NE 16
#define BATCH 8192
#define XP 516   // padded x row stride in floats (516 mod 32 = 4 -> 2-way-free gathers)

typedef __attribute__((ext_vector_type(8))) short bf16x8;
typedef __attribute__((ext_vector_type(4))) float f32x4;

static __device__ __forceinline__ ushort bf16_bits(__hip_bfloat16 h) {
  union { __hip_bfloat16 b; ushort u; } cv; cv.b = h; return cv.u;
}

// ---------------- Kernel 1: fused prep = B-fragments + per-node argmax --------------
__global__ __launch_bounds__(256) void prep_kernel(
    const float* __restrict__ T, const float* __restrict__ L,
    ushort* __restrict__ Bfrag, float* __restrict__ tmax, int* __restrict__ dstar) {
  const int tid = threadIdx.x;
  const int bid = blockIdx.x;

  // --- L -> B-fragments [kc][hl][cf][lane][8] bf16 hi/lo ---
  {
    const int i = bid * 256 + tid;  // 0..262143
    const int j = i & 7;
    const int lane = (i >> 3) & 63;
    const int cf = (i >> 9) & 7;
    const int hl = (i >> 12) & 1;
    const int kc = i >> 13;
    const int k = kc * 32 + (lane >> 4) * 8 + j;
    const int c = cf * 16 + (lane & 15);
    const float val = (c < NC) ? L[(size_t)k * NC + c] : 0.0f;
    const __hip_bfloat16 hb = __float2bfloat16(val);
    ushort outv;
    if (hl == 0) {
      outv = bf16_bits(hb);
    } else {
      const __hip_bfloat16 lb = __float2bfloat16(val - __bfloat162float(hb));
      outv = bf16_bits(lb);
    }
    Bfrag[i] = outv;
  }

  // --- per-node argmax/max over IN_DIM: wave 0 of blocks 0..1007 ---
  if (bid < NE * NN && tid < 64) {
    const float4* row = reinterpret_cast<const float4*>(T + (size_t)bid * IN_DIM);
    const int lane = tid;
    float best = -INFINITY;
    int bidx = 0;
#pragma unroll
    for (int i = 0; i < 2; ++i) {
      const int f4 = lane + 64 * i;
      const float4 v = row[f4];
      const int base = f4 * 4;
      if (v.x > best) { best = v.x; bidx = base; }
      if (v.y > best) { best = v.y; bidx = base + 1; }
      if (v.z > best) { best = v.z; bidx = base + 2; }
      if (v.w > best) { best = v.w; bidx = base + 3; }
    }
#pragma unroll
    for (int off = 32; off; off >>= 1) {
      const float ov = __shfl_xor(best, off);
      const int oi = __shfl_xor(bidx, off);
      if (ov > best || (ov == best && oi < bidx)) { best = ov; bidx = oi; }
    }
    if (lane == 0) {
      tmax[bid] = best;
      dstar[bid] = bidx;
    }
  }
}

// ---------------- Kernel F: 32 rows/block, 8 waves; wave = 4 kc x 2 row-tiles -------
__global__ __launch_bounds__(512, 2) void forest_fused_kernel(
    const float* __restrict__ x, const ushort* __restrict__ Bfrag,
    const float* __restrict__ tmaxg, const int* __restrict__ dstarg,
    float* __restrict__ out) {
  __shared__ __align__(16) float xl[32 * XP];          // 66048 B
  __shared__ float tl[NE * NN];                        // 4032 B
  __shared__ int dl[NE * NN];                          // 4032 B
  __shared__ __align__(16) float red[8 * 16 * 128];    // 65536 B (no xl alias!)
  const int tid = threadIdx.x;
  const int b0 = blockIdx.x * 32;
  const int w = tid >> 6, lane = tid & 63;

  // ---- stage 32 x rows (f32 exact) + node tables ----
  {
    const float4* xg = reinterpret_cast<const float4*>(x + (size_t)b0 * IN_DIM);
#pragma unroll
    for (int i = 0; i < 8; ++i) {
      const int idx = tid + i * 512;    // 0..4095
      const int r = idx >> 7, c4 = idx & 127;
      *reinterpret_cast<float4*>(&xl[r * XP + c4 * 4]) = xg[r * 128 + c4];
    }
    for (int i = tid; i < NE * NN; i += 512) { tl[i] = tmaxg[i]; dl[i] = dstarg[i]; }
  }
  __syncthreads();

  const int r = lane & 15;
  const int lgq = lane >> 4;
  const float* xr0 = &xl[r * XP];
  const float* xr1 = &xl[(r + 16) * XP];
  const bf16x8* bf = reinterpret_cast<const bf16x8*>(Bfrag);

  // A-gen: verbatim r8 math, parameterized by x-row pointer
  auto agen = [&](const float* xr, int lg, const float* te, const int* de,
                  bf16x8& Ah, bf16x8& Al) {
    const float s1 = floorf(te[0] - xr[de[0]]);
    const int n2 = 1 + (lg >> 2), n3 = 3 + (lg >> 1), n4 = 7 + lg;
    const float s2 = floorf(te[n2] - xr[de[n2]]);
    const float s3 = floorf(te[n3] - xr[de[n3]]);
    const float s4 = floorf(te[n4] - xr[de[n4]]);
    const int n5 = 15 + 2 * lg, n6 = 31 + 4 * lg;
    const float s5a = floorf(te[n5] - xr[de[n5]]);
    const float s5b = floorf(te[n5 + 1] - xr[de[n5 + 1]]);
    const float s60 = floorf(te[n6] - xr[de[n6]]);
    const float s61 = floorf(te[n6 + 1] - xr[de[n6 + 1]]);
    const float s62 = floorf(te[n6 + 2] - xr[de[n6 + 2]]);
    const float s63 = floorf(te[n6 + 3] - xr[de[n6 + 3]]);
    const float f1 = ((lg >> 2) & 1) ? 1.0f - s1 : s1;
    const float f2 = ((lg >> 1) & 1) ? 1.0f - s2 : s2;
    const float f3 = (lg & 1) ? 1.0f - s3 : s3;
    const float stem = f1 * f2 * f3;
    const float qa = stem * s4, qb = stem * (1.0f - s4);
    const float w00 = qa * s5a, w01 = qa * (1.0f - s5a);
    const float w10 = qb * s5b, w11 = qb * (1.0f - s5b);
    float p[8];
    p[0] = w00 * s60; p[1] = w00 * (1.0f - s60);
    p[2] = w01 * s61; p[3] = w01 * (1.0f - s61);
    p[4] = w10 * s62; p[5] = w10 * (1.0f - s62);
    p[6] = w11 * s63; p[7] = w11 * (1.0f - s63);
    union { ushort u[8]; bf16x8 v; } H, Lo;
#pragma unroll
    for (int i2 = 0; i2 < 8; ++i2) {
      const __hip_bfloat16 hb = __float2bfloat16(p[i2]);
      const float hf = __bfloat162float(hb);
      H.u[i2] = bf16_bits(hb);
      Lo.u[i2] = bf16_bits(__float2bfloat16(p[i2] - hf));
    }
    Ah = H.v; Lo.v; Al = Lo.v;
  };

  f32x4 acc0[8], acc1[8];
#pragma unroll
  for (int cf = 0; cf < 8; ++cf) { acc0[cf] = (f32x4)0.0f; acc1[cf] = (f32x4)0.0f; }

  for (int t = 0; t < 4; ++t) {
    const int kc = w * 4 + t;
    const int e = kc >> 1;
    const int lg = (kc & 1) * 4 + lgq;

    // ---- issue 16 B loads up front; A-gen x2 hides L2 latency ----
    const size_t bbase = (size_t)kc * 1024;
    bf16x8 BH[8], BL[8];
#pragma unroll
    for (int cf = 0; cf < 8; ++cf) {
      BH[cf] = bf[bbase + (size_t)cf * 64 + lane];
      BL[cf] = bf[bbase + 512 + (size_t)cf * 64 + lane];
    }

    const float* te = &tl[e * NN];
    const int* de = &dl[e * NN];
    bf16x8 Ah, Al;

    agen(xr0, lg, te, de, Ah, Al);
#pragma unroll
    for (int cf = 0; cf < 8; ++cf) {
      acc0[cf] = __builtin_amdgcn_mfma_f32_16x16x32_bf16(Ah, BH[cf], acc0[cf], 0, 0, 0);
      acc0[cf] = __builtin_amdgcn_mfma_f32_16x16x32_bf16(Al, BH[cf], acc0[cf], 0, 0, 0);
      acc0[cf] = __builtin_amdgcn_mfma_f32_16x16x32_bf16(Ah, BL[cf], acc0[cf], 0, 0, 0);
      acc0[cf] = __builtin_amdgcn_mfma_f32_16x16x32_bf16(Al, BL[cf], acc0[cf], 0, 0, 0);
    }
    agen(xr1, lg, te, de, Ah, Al);
#pragma unroll
    for (int cf = 0; cf < 8; ++cf) {
      acc1[cf] = __builtin_amdgcn_mfma_f32_16x16x32_bf16(Ah, BH[cf], acc1[cf], 0, 0, 0);
      acc1[cf] = __builtin_amdgcn_mfma_f32_16x16x32_bf16(Al, BH[cf], acc1[cf], 0, 0, 0);
      acc1[cf] = __builtin_amdgcn_mfma_f32_16x16x32_bf16(Ah, BL[cf], acc1[cf], 0, 0, 0);
      acc1[cf] = __builtin_amdgcn_mfma_f32_16x16x32_bf16(Al, BL[cf], acc1[cf], 0, 0, 0);
    }
  }

  // ---- epilogue: two passes (rows 0-15, then 16-31) through one 64 KB red buffer ---
  const int rlo = (lane >> 4) * 4;
  const int cl = lane & 15;
  const int rr = tid >> 5;   // 0..15
  const int cg = tid & 31;   // 4 cols each

  auto epi = [&](const f32x4 (&ac)[8], int rowbase) {
#pragma unroll
    for (int cf = 0; cf < 8; ++cf)
#pragma unroll
      for (int jj = 0; jj < 4; ++jj)
        red[(w * 16 + rlo + jj) * 128 + cf * 16 + cl] = ac[cf][jj];
    __syncthreads();
    float v[4];
#pragma unroll
    for (int j = 0; j < 4; ++j) {
      const int c = cg * 4 + j;
      float s = red[(0 * 16 + rr) * 128 + c];
#pragma unroll
      for (int pw = 1; pw < 8; ++pw) s += red[(pw * 16 + rr) * 128 + c];
      v[j] = s;
    }
    float m = -INFINITY;
#pragma unroll
    for (int j = 0; j < 4; ++j)
      if (cg * 4 + j < NC) m = fmaxf(m, v[j]);
#pragma unroll
    for (int off = 1; off < 32; off <<= 1) m = fmaxf(m, __shfl_xor(m, off));
    float ev[4];
    float ss = 0.0f;
#pragma unroll
    for (int j = 0; j < 4; ++j) {
      ev[j] = (cg * 4 + j < NC) ? __expf(v[j] - m) : 0.0f;
      ss += ev[j];
    }
#pragma unroll
    for (int off = 1; off < 32; off <<= 1) ss += __shfl_xor(ss, off);
    const float inv = 1.0f / ss;
    if (cg < 25) {
      float* orow = out + (size_t)(b0 + rowbase + rr) * NC + cg * 4;
      *reinterpret_cast<float4*>(orow) =
          make_float4(ev[0] * inv, ev[1] * inv, ev[2] * inv, ev[3] * inv);
    }
  };

  epi(acc0, 0);
  __syncthreads();   // pass-0 reads done before pass-1 overwrites red
  epi(acc1, 16);
}

extern "C" void kernel_launch(void* const* d_in, const int* in_sizes, int n_in,
                              void* d_out, int out_size, void* d_ws, size_t ws_size,
                              hipStream_t stream) {
  const float* x = (const float*)d_in[0];  // (8192, 512)
  const float* T = (const float*)d_in[1];  // (16, 63, 512)
  const float* L = (const float*)d_in[2];  // (16, 64, 100)
  float* out = (float*)d_out;              // (8192, 100)

  char* ws = (char*)d_ws;
  ushort* Bfrag = (ushort*)ws;              // 262144 bf16 = 524288 B
  float* tmax = (float*)(ws + 524288);      // 1008 f32
  int* dstar = (int*)(ws + 528384);         // 1008 i32

  prep_kernel<<<1024, 256, 0, stream>>>(T, L, Bfrag, tmax, dstar);
  forest_fused_kernel<<<BATCH / 32, 512, 0, stream>>>(x, Bfrag, tmax, dstar, out);
}